// Round 4
// baseline (1315.085 us; speedup 1.0000x reference)
//
#include <hip/hip_runtime.h>
#include <hip/hip_fp16.h>

// Problem constants
#define B_   64
#define T_   512
#define I_   128
#define H_   256
#define G4_  1024   // 4*H
#define R_   20
#define DA_  50
#define C_   10

typedef _Float16 half2_t __attribute__((ext_vector_type(2)));

__device__ __forceinline__ float fsigmoid(float x) {
  return __fdividef(1.0f, 1.0f + __expf(-x));
}
__device__ __forceinline__ float ftanh(float x) {
  return 1.0f - __fdividef(2.0f, __expf(2.0f * x) + 1.0f);
}

// ---------------------------------------------------------------------------
// K0: pack W_hh [256][1024] fp32 -> Wq[g][k2] half2 (column-major per gate col)
// ---------------------------------------------------------------------------
__global__ __launch_bounds__(256) void k0_pack(const float* __restrict__ Whh,
                                               half2_t* __restrict__ Wq) {
  int idx = blockIdx.x * 256 + threadIdx.x;   // 0..131071
  int g = idx & 1023, k2 = idx >> 10;
  half2_t h;
  h.x = (_Float16)Whh[(2 * k2) * G4_ + g];
  h.y = (_Float16)Whh[(2 * k2 + 1) * G4_ + g];
  Wq[g * 128 + k2] = h;
}

// ---------------------------------------------------------------------------
// K_init: zero the h-exchange mailboxes
// ---------------------------------------------------------------------------
__global__ __launch_bounds__(256) void k_init(unsigned long long* __restrict__ Hx) {
  int i = blockIdx.x * 256 + threadIdx.x;   // 16384 slots
  Hx[i] = 0ull;
}

// ---------------------------------------------------------------------------
// K1: S = (tanh(x@W1^T + b1))@W2^T + b2, layout S[B,R,T].
// ---------------------------------------------------------------------------
__global__ __launch_bounds__(256) void k1_scores(const float* __restrict__ x,
                                                 const float* __restrict__ W1,
                                                 const float* __restrict__ b1,
                                                 const float* __restrict__ W2,
                                                 const float* __restrict__ b2,
                                                 float* __restrict__ S) {
  __shared__ float xs[64][129];
  __shared__ float w1s[128][64];
  __shared__ float a1s[64][53];
  int blk = blockIdx.x;
  int tid = threadIdx.x;
  int row0 = blk * 64;
  const float4* xv = (const float4*)(x + (size_t)row0 * I_);
#pragma unroll
  for (int ch = 0; ch < 8; ch++) {
    int fidx = ch * 256 + tid;
    int r = fidx >> 5, k4 = (fidx & 31) << 2;
    float4 f = xv[fidx];
    xs[r][k4] = f.x; xs[r][k4 + 1] = f.y; xs[r][k4 + 2] = f.z; xs[r][k4 + 3] = f.w;
  }
  const float4* w1v = (const float4*)W1;
#pragma unroll
  for (int ch = 0; ch < 7; ch++) {
    int fidx = ch * 256 + tid;
    if (fidx < 1600) {
      int d = fidx >> 5, k4 = (fidx & 31) << 2;
      float4 f = w1v[fidx];
      w1s[k4][d] = f.x; w1s[k4 + 1][d] = f.y; w1s[k4 + 2][d] = f.z; w1s[k4 + 3][d] = f.w;
    }
  }
  __syncthreads();
  int ty = tid >> 4, tx = tid & 15;
  float acc[4][4] = {};
#pragma unroll 4
  for (int k = 0; k < I_; k++) {
    float a0 = xs[4 * ty][k], a1 = xs[4 * ty + 1][k];
    float a2 = xs[4 * ty + 2][k], a3 = xs[4 * ty + 3][k];
    float4 bq = *(const float4*)&w1s[k][tx << 2];
    acc[0][0] += a0 * bq.x; acc[0][1] += a0 * bq.y; acc[0][2] += a0 * bq.z; acc[0][3] += a0 * bq.w;
    acc[1][0] += a1 * bq.x; acc[1][1] += a1 * bq.y; acc[1][2] += a1 * bq.z; acc[1][3] += a1 * bq.w;
    acc[2][0] += a2 * bq.x; acc[2][1] += a2 * bq.y; acc[2][2] += a2 * bq.z; acc[2][3] += a2 * bq.w;
    acc[3][0] += a3 * bq.x; acc[3][1] += a3 * bq.y; acc[3][2] += a3 * bq.z; acc[3][3] += a3 * bq.w;
  }
#pragma unroll
  for (int i = 0; i < 4; i++) {
#pragma unroll
    for (int j = 0; j < 4; j++) {
      int col = (tx << 2) + j;
      if (col < DA_) a1s[4 * ty + i][col] = tanhf(acc[i][j] + b1[col]);
    }
  }
  __syncthreads();
  int row = tid & 63, rq = tid >> 6;
  int bt = row0 + row;
  int b = bt >> 9, t = bt & 511;
#pragma unroll
  for (int m = 0; m < 5; m++) {
    int r = rq + (m << 2);
    float acc2 = b2[r];
#pragma unroll 10
    for (int d = 0; d < DA_; d++) acc2 += a1s[row][d] * W2[r * DA_ + d];
    S[((size_t)(b * R_ + r)) * T_ + t] = acc2;
  }
}

// ---------------------------------------------------------------------------
// K2: per (b,r): m = max_t S; E = exp(S-m); invd[t] = 1/cumsum(E)[t]
// ---------------------------------------------------------------------------
__global__ __launch_bounds__(64) void k2_prefix(const float* __restrict__ S,
                                                float* __restrict__ E,
                                                float* __restrict__ invd) {
  int br = blockIdx.x;
  int l = threadIdx.x;
  const float* Sr = S + (size_t)br * T_;
  float v[8];
  float m = -1e30f;
#pragma unroll
  for (int c = 0; c < 8; c++) {
    v[c] = Sr[c * 64 + l];
    m = fmaxf(m, v[c]);
  }
#pragma unroll
  for (int off = 32; off; off >>= 1) m = fmaxf(m, __shfl_xor(m, off));
  float carry = 0.f;
  for (int c = 0; c < 8; c++) {
    float e = expf(v[c] - m);
    float s = e;
#pragma unroll
    for (int off = 1; off < 64; off <<= 1) {
      float u = __shfl_up(s, off);
      if (l >= off) s += u;
    }
    E[(size_t)br * T_ + c * 64 + l] = e;
    invd[(size_t)br * T_ + c * 64 + l] = 1.f / (carry + s);
    carry += __shfl(s, 63);
  }
}

// ---------------------------------------------------------------------------
// K3a: per (b, chunk): P[b][c][r][i] = sum_{t in chunk} E[b,r,t] * x[b,t,i]
// ---------------------------------------------------------------------------
__global__ __launch_bounds__(128) void k3a(const float* __restrict__ x,
                                           const float* __restrict__ E,
                                           float* __restrict__ P) {
  int b = blockIdx.x >> 3, c = blockIdx.x & 7;
  int i = threadIdx.x;
  int t0 = c * 64;
  __shared__ float es[2][R_];
  float acc[R_];
#pragma unroll
  for (int r = 0; r < R_; r++) acc[r] = 0.f;
  float rE = 0.f;
  if (i < R_) rE = E[((size_t)(b * R_ + i)) * T_ + t0];
  const float* xb = x + (size_t)b * T_ * I_;
  float xv = xb[(size_t)t0 * I_ + i];
  int buf = 0;
  for (int tt = 0; tt < 64; tt++) {
    if (i < R_) es[buf][i] = rE;
    __syncthreads();
    if (tt + 1 < 64) {
      if (i < R_) rE = E[((size_t)(b * R_ + i)) * T_ + t0 + tt + 1];
    }
    float xcur = xv;
    if (tt + 1 < 64) xv = xb[(size_t)(t0 + tt + 1) * I_ + i];
#pragma unroll
    for (int r = 0; r < R_; r++) acc[r] += es[buf][r] * xcur;
    buf ^= 1;
  }
#pragma unroll
  for (int r = 0; r < R_; r++)
    P[(size_t)((b * 8 + c) * R_ + r) * I_ + i] = acc[r];
}

// ---------------------------------------------------------------------------
// K3b: exclusive prefix of P over chunks, per (b,r,i). In place.
// ---------------------------------------------------------------------------
__global__ __launch_bounds__(256) void k3b(float* __restrict__ P) {
  int gid = blockIdx.x * 256 + threadIdx.x;
  int i = gid & 127;
  int r = (gid >> 7) % R_;
  int b = gid / (R_ * I_);
  float s = 0.f;
#pragma unroll
  for (int c = 0; c < 8; c++) {
    size_t idx = (size_t)((b * 8 + c) * R_ + r) * I_ + i;
    float v = P[idx];
    P[idx] = s;
    s += v;
  }
}

// ---------------------------------------------------------------------------
// K3c: per (b, chunk): acc init from P prefix, then 64 steps producing M.
// ---------------------------------------------------------------------------
__global__ __launch_bounds__(128) void k3c(const float* __restrict__ x,
                                           const float* __restrict__ E,
                                           const float* __restrict__ invd,
                                           const float* __restrict__ P,
                                           float* __restrict__ M) {
  int b = blockIdx.x >> 3, c = blockIdx.x & 7;
  int i = threadIdx.x;
  int t0 = c * 64;
  __shared__ float es[2][R_], ds[2][R_];
  float acc[R_];
#pragma unroll
  for (int r = 0; r < R_; r++)
    acc[r] = P[(size_t)((b * 8 + c) * R_ + r) * I_ + i];
  float rE = 0.f, rD = 0.f;
  if (i < R_)
    rE = E[((size_t)(b * R_ + i)) * T_ + t0];
  else if (i < 2 * R_)
    rD = invd[((size_t)(b * R_ + (i - R_))) * T_ + t0];
  const float* xb = x + (size_t)b * T_ * I_;
  float xv = xb[(size_t)t0 * I_ + i];
  int buf = 0;
  for (int tt = 0; tt < 64; tt++) {
    if (i < R_) es[buf][i] = rE;
    else if (i < 2 * R_) ds[buf][i - R_] = rD;
    __syncthreads();
    if (tt + 1 < 64) {
      if (i < R_)
        rE = E[((size_t)(b * R_ + i)) * T_ + t0 + tt + 1];
      else if (i < 2 * R_)
        rD = invd[((size_t)(b * R_ + (i - R_))) * T_ + t0 + tt + 1];
    }
    float xcur = xv;
    if (tt + 1 < 64) xv = xb[(size_t)(t0 + tt + 1) * I_ + i];
    float s = 0.f;
#pragma unroll
    for (int r = 0; r < R_; r++) {
      acc[r] += es[buf][r] * xcur;
      s += acc[r] * ds[buf][r];
    }
    M[(size_t)b * T_ * I_ + (size_t)(t0 + tt) * I_ + i] = s * (1.0f / R_);
    buf ^= 1;
  }
}

// ---------------------------------------------------------------------------
// K4: gx[row][g] = M[row,:] @ W_ih[:,g] + b[g].  Output fp16.
// ---------------------------------------------------------------------------
__global__ __launch_bounds__(256) void k4_gemm(const float* __restrict__ Mm,
                                               const float* __restrict__ Wih,
                                               const float* __restrict__ bg,
                                               __half* __restrict__ gx) {
  __shared__ float As[I_][64];
  __shared__ float Bs[I_][64];
  int row0 = blockIdx.x * 64, col0 = blockIdx.y * 64;
  int tid = threadIdx.x;
#pragma unroll
  for (int ch = 0; ch < 8; ch++) {
    int fidx = ch * 256 + tid;
    int r = fidx >> 5;
    int kk = (fidx & 31) << 2;
    float4 f = ((const float4*)(Mm + (size_t)(row0 + r) * I_))[fidx & 31];
    As[kk + 0][r] = f.x;
    As[kk + 1][r] = f.y;
    As[kk + 2][r] = f.z;
    As[kk + 3][r] = f.w;
  }
#pragma unroll
  for (int ch = 0; ch < 8; ch++) {
    int fidx = ch * 256 + tid;
    int k = fidx >> 4;
    int c4 = (fidx & 15) << 2;
    float4 f = *((const float4*)(Wih + (size_t)k * G4_ + col0 + c4));
    *((float4*)&Bs[k][c4]) = f;
  }
  __syncthreads();
  int ty = tid >> 4, tx = tid & 15;
  float acc[4][4] = {};
#pragma unroll 4
  for (int k = 0; k < I_; k++) {
    float4 a = *((float4*)&As[k][ty << 2]);
    float4 bq = *((float4*)&Bs[k][tx << 2]);
    acc[0][0] += a.x * bq.x; acc[0][1] += a.x * bq.y; acc[0][2] += a.x * bq.z; acc[0][3] += a.x * bq.w;
    acc[1][0] += a.y * bq.x; acc[1][1] += a.y * bq.y; acc[1][2] += a.y * bq.z; acc[1][3] += a.y * bq.w;
    acc[2][0] += a.z * bq.x; acc[2][1] += a.z * bq.y; acc[2][2] += a.z * bq.z; acc[2][3] += a.z * bq.w;
    acc[3][0] += a.w * bq.x; acc[3][1] += a.w * bq.y; acc[3][2] += a.w * bq.z; acc[3][3] += a.w * bq.w;
  }
#pragma unroll
  for (int ii = 0; ii < 4; ii++) {
#pragma unroll
    for (int jj = 0; jj < 4; jj++) {
      int row = row0 + (ty << 2) + ii;
      int col = col0 + (tx << 2) + jj;
      gx[(size_t)row * G4_ + col] = __float2half(acc[ii][jj] + bg[col]);
    }
  }
}

// ---------------------------------------------------------------------------
// K5: LSTM scan. 2 blocks per batch (grid 128 x 512 threads).
// KEY FIX: amdgpu_waves_per_eu(2,2) pins MAX waves/EU = 2, so the register
// allocator's occupancy target is 2 waves/EU (256-VGPR budget) and it has no
// incentive to spill the 128 W VGPRs to scratch (rounds 0-3: allocator
// targeted 6-8 waves/EU and spilled W every time -> scratch-L2-bound).
// sched_barrier(0) every 8 DOT4s caps peak pressure (W 128 + hq <=32 + ovh).
// ---------------------------------------------------------------------------
#define BCH2(u) __builtin_bit_cast(half2_t, (u))
#define LDW(j) uint4 w##j = wp[j];
#define DOT4(j)                                                         \
  {                                                                     \
    uint4 hq = hb[j];                                                   \
    a0 = __builtin_amdgcn_fdot2(BCH2(w##j.x), BCH2(hq.x), a0, false);   \
    a1 = __builtin_amdgcn_fdot2(BCH2(w##j.y), BCH2(hq.y), a1, false);   \
    a2 = __builtin_amdgcn_fdot2(BCH2(w##j.z), BCH2(hq.z), a2, false);   \
    a3 = __builtin_amdgcn_fdot2(BCH2(w##j.w), BCH2(hq.w), a3, false);   \
  }

__global__ __launch_bounds__(512)
__attribute__((amdgpu_waves_per_eu(2, 2)))
void k5_lstm(
    const __half* __restrict__ gx, const half2_t* __restrict__ Wq,
    unsigned long long* __restrict__ Hx, float* __restrict__ hT) {
  int b = blockIdx.x & 63;
  int p = blockIdx.x >> 6;               // partition 0/1 (units p*128..+127)
  int tid = threadIdx.x;
  int wave = tid >> 6;                   // 0..7
  int lane = tid & 63;
  int gate = lane & 3;                   // 0=i 1=f 2=g 3=o
  int u = p * 128 + wave * 16 + (lane >> 2);   // unit 0..255
  int gcol = gate * H_ + u;              // gate column 0..1023

  __shared__ __align__(16) unsigned hs32[2][128];   // h double-buffer (fp16 x2)

  // Load W column into 32 named uint4 (= 128 VGPRs held as SSA values).
  const uint4* wp = (const uint4*)(Wq + (size_t)gcol * 128);
  LDW(0)  LDW(1)  LDW(2)  LDW(3)  LDW(4)  LDW(5)  LDW(6)  LDW(7)
  LDW(8)  LDW(9)  LDW(10) LDW(11) LDW(12) LDW(13) LDW(14) LDW(15)
  LDW(16) LDW(17) LDW(18) LDW(19) LDW(20) LDW(21) LDW(22) LDW(23)
  LDW(24) LDW(25) LDW(26) LDW(27) LDW(28) LDW(29) LDW(30) LDW(31)

  // h0 = 1.0 for all units
  if (tid < 128) hs32[0][tid] = 0x3C003C00u;

  float cstate = 1.0f;                   // valid on leader lanes (gate==0)
  const __half* gxb = gx + (size_t)b * T_ * G4_ + gcol;
  float gxv = (float)gxb[0];

  for (int t = 0; t < T_; t++) {
    // prefetch next step's gate input (hidden under this step's compute)
    float nextgx = 0.f;
    if (t + 1 < T_) nextgx = (float)gxb[(size_t)(t + 1) * G4_];

    // poll remote partition's 64 packets (8 pollers per wave: lane&7==0)
    if (t > 0 && (lane & 7) == 0) {
      int j = wave * 8 + (lane >> 3);
      const unsigned long long* src =
          Hx + ((((size_t)(t & 1) * 64 + b) * 2) + (p ^ 1)) * 64 + j;
      unsigned long long v;
      do {
        v = __hip_atomic_load(src, __ATOMIC_RELAXED, __HIP_MEMORY_SCOPE_AGENT);
      } while ((unsigned)(v >> 32) != (unsigned)t);
      hs32[t & 1][(p ^ 1) * 64 + j] = (unsigned)v;
    }
    __syncthreads();   // orders h-writes (local leaders + pollers) vs reads

    // full-K dot: 32 uniform-address b128 LDS reads (broadcast) + 128 fdot2
    const uint4* hb = (const uint4*)hs32[t & 1];
    float a0 = 0.f, a1 = 0.f, a2 = 0.f, a3 = 0.f;
    DOT4(0)  DOT4(1)  DOT4(2)  DOT4(3)  DOT4(4)  DOT4(5)  DOT4(6)  DOT4(7)
    __builtin_amdgcn_sched_barrier(0);
    DOT4(8)  DOT4(9)  DOT4(10) DOT4(11) DOT4(12) DOT4(13) DOT4(14) DOT4(15)
    __builtin_amdgcn_sched_barrier(0);
    DOT4(16) DOT4(17) DOT4(18) DOT4(19) DOT4(20) DOT4(21) DOT4(22) DOT4(23)
    __builtin_amdgcn_sched_barrier(0);
    DOT4(24) DOT4(25) DOT4(26) DOT4(27) DOT4(28) DOT4(29) DOT4(30) DOT4(31)
    float s = (a0 + a1) + (a2 + a3) + gxv;

    // gather f,g,o preacts to leader lane (gate==0) of each 4-lane group
    float f1 = __shfl_down(s, 1);
    float f2 = __shfl_down(s, 2);
    float f3 = __shfl_down(s, 3);
    unsigned hu = 0;
    if (gate == 0) {
      float vi = fsigmoid(s);
      float vf = fsigmoid(f1);
      float vg = ftanh(f2);
      float vo = fsigmoid(f3);
      cstate = vf * cstate + vi * vg;
      float h = vo * ftanh(cstate);
      hu = (unsigned)__half_as_ushort(__float2half(h));
      if (t == T_ - 1) hT[b * H_ + u] = h;
    }
    // pack units (u, u+1): leader at lane, partner leader at lane+4
    unsigned hup = (unsigned)__shfl_down((int)hu, 4);
    if ((lane & 7) == 0 && (t + 1) < T_) {
      unsigned pk = hu | (hup << 16);
      int j = wave * 8 + (lane >> 3);
      unsigned long long pkt =
          (unsigned long long)pk |
          ((unsigned long long)(unsigned)(t + 1) << 32);
      unsigned long long* dst =
          Hx + ((((size_t)((t + 1) & 1) * 64 + b) * 2) + p) * 64 + j;
      __hip_atomic_store(dst, pkt, __ATOMIC_RELAXED, __HIP_MEMORY_SCOPE_AGENT);
      hs32[(t + 1) & 1][p * 64 + j] = pk;   // local copy for next step
    }
    // no second barrier: writes target the other hs buffer; the next step's
    // __syncthreads orders them before all reads.
    gxv = nextgx;
  }
}

// ---------------------------------------------------------------------------
// K6: logits = hT @ Wfc^T + bfc; softmax.  One wave per b.
// ---------------------------------------------------------------------------
__global__ __launch_bounds__(64) void k6_head(const float* __restrict__ hT,
                                              const float* __restrict__ Wfc,
                                              const float* __restrict__ bfc,
                                              float* __restrict__ out) {
  int b = blockIdx.x, l = threadIdx.x;
  const float* h = hT + b * H_;
  float p[C_];
#pragma unroll
  for (int c = 0; c < C_; c++) p[c] = 0.f;
#pragma unroll
  for (int q = 0; q < 4; q++) {
    float hv = h[q * 64 + l];
#pragma unroll
    for (int c = 0; c < C_; c++) p[c] += hv * Wfc[c * H_ + q * 64 + l];
  }
#pragma unroll
  for (int c = 0; c < C_; c++)
    for (int off = 32; off; off >>= 1) p[c] += __shfl_xor(p[c], off);
  if (l == 0) {
    float m = -1e30f, e[C_], sum = 0.f;
    for (int c = 0; c < C_; c++) { p[c] += bfc[c]; m = fmaxf(m, p[c]); }
    for (int c = 0; c < C_; c++) { e[c] = expf(p[c] - m); sum += e[c]; }
    for (int c = 0; c < C_; c++) out[b * C_ + c] = e[c] / sum;
  }
}

// ---------------------------------------------------------------------------
// Workspace layout (float offsets):
//   Hx    [2][64][2][64] u64 = dwords [0, 32768)  (aliases S; S dead after k2)
//   S     [B,R,T]        wsf + 0
//   E     [B,R,T]        wsf + 655360
//   INVD  [B,R,T]        wsf + 1310720
//   M     [B,T,I]        wsf + 1966080
//   hT    [B,H]          wsf + 6160384
//   Wq    [1024][128]h2  wsf + 6176768  (131072 dwords)
//   gx    [B,T,4H] fp16  wsf + 6307840  (16777216 dwords)
//   P     [B][8][R][I]   aliases gx region (P dead before k4 writes gx)
// ---------------------------------------------------------------------------
extern "C" void kernel_launch(void* const* d_in, const int* in_sizes, int n_in,
                              void* d_out, int out_size, void* d_ws, size_t ws_size,
                              hipStream_t stream) {
  const float* x   = (const float*)d_in[0];
  const float* Wih = (const float*)d_in[1];
  const float* Whh = (const float*)d_in[2];
  const float* bg  = (const float*)d_in[3];
  const float* W1  = (const float*)d_in[4];
  const float* b1  = (const float*)d_in[5];
  const float* W2  = (const float*)d_in[6];
  const float* b2  = (const float*)d_in[7];
  const float* Wfc = (const float*)d_in[8];
  const float* bfc = (const float*)d_in[9];
  float* out = (float*)d_out;

  float* wsf = (float*)d_ws;
  unsigned long long* Hx = (unsigned long long*)wsf;
  float* S    = wsf;
  float* E    = wsf + 655360;
  float* INVD = wsf + 1310720;
  float* Mm   = wsf + 1966080;
  float* hT   = wsf + 6160384;
  half2_t* Wq = (half2_t*)(wsf + 6176768);
  __half* gx  = (__half*)(wsf + 6307840);
  float* P    = wsf + 6307840;           // aliases gx region (disjoint in time)

  hipLaunchKernelGGL(k0_pack,   dim3(512),     dim3(256), 0, stream, Whh, Wq);
  hipLaunchKernelGGL(k1_scores, dim3(512),     dim3(256), 0, stream, x, W1, b1, W2, b2, S);
  hipLaunchKernelGGL(k2_prefix, dim3(B_ * R_), dim3(64),  0, stream, S, E, INVD);
  hipLaunchKernelGGL(k3a,       dim3(512),     dim3(128), 0, stream, x, E, P);
  hipLaunchKernelGGL(k3b,       dim3(640),     dim3(256), 0, stream, P);
  hipLaunchKernelGGL(k3c,       dim3(512),     dim3(128), 0, stream, x, E, INVD, P, Mm);
  hipLaunchKernelGGL(k4_gemm,   dim3(512, 16), dim3(256), 0, stream, Mm, Wih, bg, gx);
  hipLaunchKernelGGL(k_init,    dim3(64),      dim3(256), 0, stream, Hx);
  hipLaunchKernelGGL(k5_lstm,   dim3(128),     dim3(512), 0, stream, gx, Wq, Hx, hT);
  hipLaunchKernelGGL(k6_head,   dim3(B_),      dim3(64),  0, stream, hT, Wfc, bfc, out);
}

// Round 5
// 1227.561 us; speedup vs baseline: 1.0713x; 1.0713x over previous
//
#include <hip/hip_runtime.h>
#include <hip/hip_fp16.h>

// Problem constants
#define B_   64
#define T_   512
#define I_   128
#define H_   256
#define G4_  1024   // 4*H
#define R_   20
#define DA_  50
#define C_   10

typedef _Float16 half2_t __attribute__((ext_vector_type(2)));

__device__ __forceinline__ float fsigmoid(float x) {
  return __fdividef(1.0f, 1.0f + __expf(-x));
}
__device__ __forceinline__ float ftanh(float x) {
  return 1.0f - __fdividef(2.0f, __expf(2.0f * x) + 1.0f);
}

// ---------------------------------------------------------------------------
// K0: pack W_hh [256][1024] fp32 -> Wq[g][k2] half2 (column-major per gate col)
// ---------------------------------------------------------------------------
__global__ __launch_bounds__(256) void k0_pack(const float* __restrict__ Whh,
                                               half2_t* __restrict__ Wq) {
  int idx = blockIdx.x * 256 + threadIdx.x;   // 0..131071
  int g = idx & 1023, k2 = idx >> 10;
  half2_t h;
  h.x = (_Float16)Whh[(2 * k2) * G4_ + g];
  h.y = (_Float16)Whh[(2 * k2 + 1) * G4_ + g];
  Wq[g * 128 + k2] = h;
}

// ---------------------------------------------------------------------------
// K_init: zero the h-exchange mailboxes
// ---------------------------------------------------------------------------
__global__ __launch_bounds__(256) void k_init(unsigned long long* __restrict__ Hx) {
  int i = blockIdx.x * 256 + threadIdx.x;   // 16384 slots
  Hx[i] = 0ull;
}

// ---------------------------------------------------------------------------
// K1: S = (tanh(x@W1^T + b1))@W2^T + b2, layout S[B,R,T].
// ---------------------------------------------------------------------------
__global__ __launch_bounds__(256) void k1_scores(const float* __restrict__ x,
                                                 const float* __restrict__ W1,
                                                 const float* __restrict__ b1,
                                                 const float* __restrict__ W2,
                                                 const float* __restrict__ b2,
                                                 float* __restrict__ S) {
  __shared__ float xs[64][129];
  __shared__ float w1s[128][64];
  __shared__ float a1s[64][53];
  int blk = blockIdx.x;
  int tid = threadIdx.x;
  int row0 = blk * 64;
  const float4* xv = (const float4*)(x + (size_t)row0 * I_);
#pragma unroll
  for (int ch = 0; ch < 8; ch++) {
    int fidx = ch * 256 + tid;
    int r = fidx >> 5, k4 = (fidx & 31) << 2;
    float4 f = xv[fidx];
    xs[r][k4] = f.x; xs[r][k4 + 1] = f.y; xs[r][k4 + 2] = f.z; xs[r][k4 + 3] = f.w;
  }
  const float4* w1v = (const float4*)W1;
#pragma unroll
  for (int ch = 0; ch < 7; ch++) {
    int fidx = ch * 256 + tid;
    if (fidx < 1600) {
      int d = fidx >> 5, k4 = (fidx & 31) << 2;
      float4 f = w1v[fidx];
      w1s[k4][d] = f.x; w1s[k4 + 1][d] = f.y; w1s[k4 + 2][d] = f.z; w1s[k4 + 3][d] = f.w;
    }
  }
  __syncthreads();
  int ty = tid >> 4, tx = tid & 15;
  float acc[4][4] = {};
#pragma unroll 4
  for (int k = 0; k < I_; k++) {
    float a0 = xs[4 * ty][k], a1 = xs[4 * ty + 1][k];
    float a2 = xs[4 * ty + 2][k], a3 = xs[4 * ty + 3][k];
    float4 bq = *(const float4*)&w1s[k][tx << 2];
    acc[0][0] += a0 * bq.x; acc[0][1] += a0 * bq.y; acc[0][2] += a0 * bq.z; acc[0][3] += a0 * bq.w;
    acc[1][0] += a1 * bq.x; acc[1][1] += a1 * bq.y; acc[1][2] += a1 * bq.z; acc[1][3] += a1 * bq.w;
    acc[2][0] += a2 * bq.x; acc[2][1] += a2 * bq.y; acc[2][2] += a2 * bq.z; acc[2][3] += a2 * bq.w;
    acc[3][0] += a3 * bq.x; acc[3][1] += a3 * bq.y; acc[3][2] += a3 * bq.z; acc[3][3] += a3 * bq.w;
  }
#pragma unroll
  for (int i = 0; i < 4; i++) {
#pragma unroll
    for (int j = 0; j < 4; j++) {
      int col = (tx << 2) + j;
      if (col < DA_) a1s[4 * ty + i][col] = tanhf(acc[i][j] + b1[col]);
    }
  }
  __syncthreads();
  int row = tid & 63, rq = tid >> 6;
  int bt = row0 + row;
  int b = bt >> 9, t = bt & 511;
#pragma unroll
  for (int m = 0; m < 5; m++) {
    int r = rq + (m << 2);
    float acc2 = b2[r];
#pragma unroll 10
    for (int d = 0; d < DA_; d++) acc2 += a1s[row][d] * W2[r * DA_ + d];
    S[((size_t)(b * R_ + r)) * T_ + t] = acc2;
  }
}

// ---------------------------------------------------------------------------
// K2: per (b,r): m = max_t S; E = exp(S-m); invd[t] = 1/cumsum(E)[t]
// ---------------------------------------------------------------------------
__global__ __launch_bounds__(64) void k2_prefix(const float* __restrict__ S,
                                                float* __restrict__ E,
                                                float* __restrict__ invd) {
  int br = blockIdx.x;
  int l = threadIdx.x;
  const float* Sr = S + (size_t)br * T_;
  float v[8];
  float m = -1e30f;
#pragma unroll
  for (int c = 0; c < 8; c++) {
    v[c] = Sr[c * 64 + l];
    m = fmaxf(m, v[c]);
  }
#pragma unroll
  for (int off = 32; off; off >>= 1) m = fmaxf(m, __shfl_xor(m, off));
  float carry = 0.f;
  for (int c = 0; c < 8; c++) {
    float e = expf(v[c] - m);
    float s = e;
#pragma unroll
    for (int off = 1; off < 64; off <<= 1) {
      float u = __shfl_up(s, off);
      if (l >= off) s += u;
    }
    E[(size_t)br * T_ + c * 64 + l] = e;
    invd[(size_t)br * T_ + c * 64 + l] = 1.f / (carry + s);
    carry += __shfl(s, 63);
  }
}

// ---------------------------------------------------------------------------
// K3a: per (b, chunk): P[b][c][r][i] = sum_{t in chunk} E[b,r,t] * x[b,t,i]
// ---------------------------------------------------------------------------
__global__ __launch_bounds__(128) void k3a(const float* __restrict__ x,
                                           const float* __restrict__ E,
                                           float* __restrict__ P) {
  int b = blockIdx.x >> 3, c = blockIdx.x & 7;
  int i = threadIdx.x;
  int t0 = c * 64;
  __shared__ float es[2][R_];
  float acc[R_];
#pragma unroll
  for (int r = 0; r < R_; r++) acc[r] = 0.f;
  float rE = 0.f;
  if (i < R_) rE = E[((size_t)(b * R_ + i)) * T_ + t0];
  const float* xb = x + (size_t)b * T_ * I_;
  float xv = xb[(size_t)t0 * I_ + i];
  int buf = 0;
  for (int tt = 0; tt < 64; tt++) {
    if (i < R_) es[buf][i] = rE;
    __syncthreads();
    if (tt + 1 < 64) {
      if (i < R_) rE = E[((size_t)(b * R_ + i)) * T_ + t0 + tt + 1];
    }
    float xcur = xv;
    if (tt + 1 < 64) xv = xb[(size_t)(t0 + tt + 1) * I_ + i];
#pragma unroll
    for (int r = 0; r < R_; r++) acc[r] += es[buf][r] * xcur;
    buf ^= 1;
  }
#pragma unroll
  for (int r = 0; r < R_; r++)
    P[(size_t)((b * 8 + c) * R_ + r) * I_ + i] = acc[r];
}

// ---------------------------------------------------------------------------
// K3b: exclusive prefix of P over chunks, per (b,r,i). In place.
// ---------------------------------------------------------------------------
__global__ __launch_bounds__(256) void k3b(float* __restrict__ P) {
  int gid = blockIdx.x * 256 + threadIdx.x;
  int i = gid & 127;
  int r = (gid >> 7) % R_;
  int b = gid / (R_ * I_);
  float s = 0.f;
#pragma unroll
  for (int c = 0; c < 8; c++) {
    size_t idx = (size_t)((b * 8 + c) * R_ + r) * I_ + i;
    float v = P[idx];
    P[idx] = s;
    s += v;
  }
}

// ---------------------------------------------------------------------------
// K3c: per (b, chunk): acc init from P prefix, then 64 steps producing M.
// ---------------------------------------------------------------------------
__global__ __launch_bounds__(128) void k3c(const float* __restrict__ x,
                                           const float* __restrict__ E,
                                           const float* __restrict__ invd,
                                           const float* __restrict__ P,
                                           float* __restrict__ M) {
  int b = blockIdx.x >> 3, c = blockIdx.x & 7;
  int i = threadIdx.x;
  int t0 = c * 64;
  __shared__ float es[2][R_], ds[2][R_];
  float acc[R_];
#pragma unroll
  for (int r = 0; r < R_; r++)
    acc[r] = P[(size_t)((b * 8 + c) * R_ + r) * I_ + i];
  float rE = 0.f, rD = 0.f;
  if (i < R_)
    rE = E[((size_t)(b * R_ + i)) * T_ + t0];
  else if (i < 2 * R_)
    rD = invd[((size_t)(b * R_ + (i - R_))) * T_ + t0];
  const float* xb = x + (size_t)b * T_ * I_;
  float xv = xb[(size_t)t0 * I_ + i];
  int buf = 0;
  for (int tt = 0; tt < 64; tt++) {
    if (i < R_) es[buf][i] = rE;
    else if (i < 2 * R_) ds[buf][i - R_] = rD;
    __syncthreads();
    if (tt + 1 < 64) {
      if (i < R_)
        rE = E[((size_t)(b * R_ + i)) * T_ + t0 + tt + 1];
      else if (i < 2 * R_)
        rD = invd[((size_t)(b * R_ + (i - R_))) * T_ + t0 + tt + 1];
    }
    float xcur = xv;
    if (tt + 1 < 64) xv = xb[(size_t)(t0 + tt + 1) * I_ + i];
    float s = 0.f;
#pragma unroll
    for (int r = 0; r < R_; r++) {
      acc[r] += es[buf][r] * xcur;
      s += acc[r] * ds[buf][r];
    }
    M[(size_t)b * T_ * I_ + (size_t)(t0 + tt) * I_ + i] = s * (1.0f / R_);
    buf ^= 1;
  }
}

// ---------------------------------------------------------------------------
// K4: gx[row][g] = M[row,:] @ W_ih[:,g] + b[g].  Output fp16.
// ---------------------------------------------------------------------------
__global__ __launch_bounds__(256) void k4_gemm(const float* __restrict__ Mm,
                                               const float* __restrict__ Wih,
                                               const float* __restrict__ bg,
                                               __half* __restrict__ gx) {
  __shared__ float As[I_][64];
  __shared__ float Bs[I_][64];
  int row0 = blockIdx.x * 64, col0 = blockIdx.y * 64;
  int tid = threadIdx.x;
#pragma unroll
  for (int ch = 0; ch < 8; ch++) {
    int fidx = ch * 256 + tid;
    int r = fidx >> 5;
    int kk = (fidx & 31) << 2;
    float4 f = ((const float4*)(Mm + (size_t)(row0 + r) * I_))[fidx & 31];
    As[kk + 0][r] = f.x;
    As[kk + 1][r] = f.y;
    As[kk + 2][r] = f.z;
    As[kk + 3][r] = f.w;
  }
#pragma unroll
  for (int ch = 0; ch < 8; ch++) {
    int fidx = ch * 256 + tid;
    int k = fidx >> 4;
    int c4 = (fidx & 15) << 2;
    float4 f = *((const float4*)(Wih + (size_t)k * G4_ + col0 + c4));
    *((float4*)&Bs[k][c4]) = f;
  }
  __syncthreads();
  int ty = tid >> 4, tx = tid & 15;
  float acc[4][4] = {};
#pragma unroll 4
  for (int k = 0; k < I_; k++) {
    float4 a = *((float4*)&As[k][ty << 2]);
    float4 bq = *((float4*)&Bs[k][tx << 2]);
    acc[0][0] += a.x * bq.x; acc[0][1] += a.x * bq.y; acc[0][2] += a.x * bq.z; acc[0][3] += a.x * bq.w;
    acc[1][0] += a.y * bq.x; acc[1][1] += a.y * bq.y; acc[1][2] += a.y * bq.z; acc[1][3] += a.y * bq.w;
    acc[2][0] += a.z * bq.x; acc[2][1] += a.z * bq.y; acc[2][2] += a.z * bq.z; acc[2][3] += a.z * bq.w;
    acc[3][0] += a.w * bq.x; acc[3][1] += a.w * bq.y; acc[3][2] += a.w * bq.z; acc[3][3] += a.w * bq.w;
  }
#pragma unroll
  for (int ii = 0; ii < 4; ii++) {
#pragma unroll
    for (int jj = 0; jj < 4; jj++) {
      int row = row0 + (ty << 2) + ii;
      int col = col0 + (tx << 2) + jj;
      gx[(size_t)row * G4_ + col] = __float2half(acc[ii][jj] + bg[col]);
    }
  }
}

// ---------------------------------------------------------------------------
// K5: LSTM scan. 4 blocks per batch (grid 256 x 512 threads).
// Partners (b, b+64, b+128, b+192) share bid%8 -> same XCD -> L2-local mailbox.
// W LIVES IN LDS (128 KiB staged once) -- no register-allocator fight:
// rounds 0-4 proved the compiler re-fetches "register-pinned" W from memory
// every step (L2-BW-bound at ~56 B/cyc/CU). LDS streams it at 256 B/clk/CU.
// Thread map: lane = uw*8 + gate*2 + kh; thread owns K-half kh of one gate
// column (256 B = 16 x uint4).  Wl[j][512]: wave reads contiguous 1 KiB per
// chunk j -> conflict-free ds_read_b128. h reads are 2-addr broadcasts.
// Mailbox: {2 x fp16 | step tag} u64 relaxed agent atomics (round-0 format).
// ---------------------------------------------------------------------------
#define BCH2(u) __builtin_bit_cast(half2_t, (u))
#define FDOT(w, h, a) __builtin_amdgcn_fdot2(BCH2(w), BCH2(h), (a), false)

__global__ __launch_bounds__(512, 1) void k5_lstm(
    const __half* __restrict__ gx, const half2_t* __restrict__ Wq,
    unsigned long long* __restrict__ Hx, float* __restrict__ hT) {
  int b = blockIdx.x & 63;
  int p = blockIdx.x >> 6;               // partition 0..3, owns units p*64..+63
  int tid = threadIdx.x;
  int wave = tid >> 6;                   // 0..7
  int lane = tid & 63;
  int kh = lane & 1;                     // k-half (0: k 0..127, 1: k 128..255)
  int gate = (lane >> 1) & 3;            // 0=i 1=f 2=g 3=o
  int uw = lane >> 3;                    // unit-in-wave 0..7
  int u = wave * 8 + uw;                 // unit in partition 0..63
  int gcol = gate * H_ + p * 64 + u;     // gate column 0..1023

  __shared__ uint4 Wl[16 * 512];                    // 128 KiB W slices
  __shared__ __align__(16) unsigned hs32[2][128];   // h double-buffer (fp16 x2)

  // Stage W into LDS (one-time). Iterate linearly over this block's Wq span
  // so global reads are coalesced; scatter into per-thread chunk layout.
  const uint4* wq4 = (const uint4*)Wq;
#pragma unroll
  for (int it = 0; it < 16; it++) {
    int lin = it * 512 + tid;            // 0..8191
    int j = lin & 15;
    int skh = (lin >> 4) & 1;
    int suw = (lin >> 5) & 7;
    int swv = (lin >> 8) & 7;
    int sgate = lin >> 11;               // 0..3
    int sgcol = sgate * H_ + p * 64 + swv * 8 + suw;
    int dst = swv * 64 + suw * 8 + sgate * 2 + skh;
    Wl[j * 512 + dst] = wq4[sgcol * 32 + skh * 16 + j];
  }
  // h0 = 1.0 for all units
  if (tid < 128) hs32[0][tid] = 0x3C003C00u;
  __syncthreads();

  // Poller role: tid<96 polls remote partition q_, slot d_.
  int qi = tid >> 5;                     // 0..2
  int q_ = qi + (qi >= p ? 1 : 0);
  int d_ = tid & 31;

  float cstate = 1.0f;                   // valid on leader lanes (lane&7)==0
  const __half* gxb = gx + (size_t)b * T_ * G4_ + gcol;
  float gxv = 0.f;
  if (!kh) gxv = (float)gxb[0];

  for (int t = 0; t < T_; t++) {
    // prefetch next step's gate input (hidden under this step's compute)
    float nextgx = 0.f;
    if (!kh && t + 1 < T_) nextgx = (float)gxb[(size_t)(t + 1) * G4_];

    // poll remote partitions' packets
    if (t > 0 && tid < 96) {
      const unsigned long long* src =
          Hx + ((size_t)(t & 1) * 64 + b) * 128 + q_ * 32 + d_;
      unsigned long long v;
      do {
        v = __hip_atomic_load(src, __ATOMIC_RELAXED, __HIP_MEMORY_SCOPE_AGENT);
      } while ((unsigned)(v >> 32) != (unsigned)t);
      hs32[t & 1][q_ * 32 + d_] = (unsigned)v;
    }
    __syncthreads();   // orders h-writes (local leaders + pollers) vs reads

    // K=128 partial dot: 16 x (W chunk from LDS, h chunk broadcast), 64 fdot2
    const uint4* hb = (const uint4*)hs32[t & 1] + kh * 16;
    float a0 = 0.f, a1 = 0.f, a2 = 0.f, a3 = 0.f;
#pragma unroll
    for (int j = 0; j < 16; j++) {
      uint4 wv = Wl[j * 512 + tid];
      uint4 hq = hb[j];
      a0 = FDOT(wv.x, hq.x, a0);
      a1 = FDOT(wv.y, hq.y, a1);
      a2 = FDOT(wv.z, hq.z, a2);
      a3 = FDOT(wv.w, hq.w, a3);
    }
    float s = (a0 + a1) + (a2 + a3);
    s += __shfl_xor(s, 1);               // combine k-halves
    s += gxv;                            // kh=0 lanes: full gate preact

    // gather gates to leader (lane&7==0): f at +2, g at +4, o at +6
    float f1 = __shfl_down(s, 2);
    float f2 = __shfl_down(s, 4);
    float f3 = __shfl_down(s, 6);
    unsigned hu = 0;
    if ((lane & 7) == 0) {
      float vi = fsigmoid(s);
      float vf = fsigmoid(f1);
      float vg = ftanh(f2);
      float vo = fsigmoid(f3);
      cstate = vf * cstate + vi * vg;
      float h = vo * ftanh(cstate);
      hu = (unsigned)__half_as_ushort(__float2half(h));
      if (t == T_ - 1) hT[b * H_ + p * 64 + u] = h;
    }
    // pack unit pair (u, u+1): partner leader is 8 lanes down
    unsigned hup = (unsigned)__shfl_down((int)hu, 8);
    if ((lane & 15) == 0 && (t + 1) < T_) {
      unsigned pk = hu | (hup << 16);
      int slot = p * 32 + wave * 4 + (lane >> 4);
      unsigned long long pkt =
          (unsigned long long)pk |
          ((unsigned long long)(unsigned)(t + 1) << 32);
      unsigned long long* dst =
          Hx + ((size_t)((t + 1) & 1) * 64 + b) * 128 + slot;
      __hip_atomic_store(dst, pkt, __ATOMIC_RELAXED, __HIP_MEMORY_SCOPE_AGENT);
      hs32[(t + 1) & 1][slot] = pk;      // local copy for next step
    }
    // no second barrier: next-step writes target the other hs buffer, and
    // the next step's __syncthreads orders them before all reads.
    gxv = nextgx;
  }
}

// ---------------------------------------------------------------------------
// K6: logits = hT @ Wfc^T + bfc; softmax.  One wave per b.
// ---------------------------------------------------------------------------
__global__ __launch_bounds__(64) void k6_head(const float* __restrict__ hT,
                                              const float* __restrict__ Wfc,
                                              const float* __restrict__ bfc,
                                              float* __restrict__ out) {
  int b = blockIdx.x, l = threadIdx.x;
  const float* h = hT + b * H_;
  float p[C_];
#pragma unroll
  for (int c = 0; c < C_; c++) p[c] = 0.f;
#pragma unroll
  for (int q = 0; q < 4; q++) {
    float hv = h[q * 64 + l];
#pragma unroll
    for (int c = 0; c < C_; c++) p[c] += hv * Wfc[c * H_ + q * 64 + l];
  }
#pragma unroll
  for (int c = 0; c < C_; c++)
    for (int off = 32; off; off >>= 1) p[c] += __shfl_xor(p[c], off);
  if (l == 0) {
    float m = -1e30f, e[C_], sum = 0.f;
    for (int c = 0; c < C_; c++) { p[c] += bfc[c]; m = fmaxf(m, p[c]); }
    for (int c = 0; c < C_; c++) { e[c] = expf(p[c] - m); sum += e[c]; }
    for (int c = 0; c < C_; c++) out[b * C_ + c] = e[c] / sum;
  }
}

// ---------------------------------------------------------------------------
// Workspace layout (float offsets):
//   Hx    [2][64][128] u64 = dwords [0, 32768)   (aliases S; S dead after k2)
//   S     [B,R,T]        wsf + 0
//   E     [B,R,T]        wsf + 655360
//   INVD  [B,R,T]        wsf + 1310720
//   M     [B,T,I]        wsf + 1966080
//   hT    [B,H]          wsf + 6160384
//   Wq    [1024][128]h2  wsf + 6176768  (131072 dwords)
//   gx    [B,T,4H] fp16  wsf + 6307840  (16777216 dwords)
//   P     [B][8][R][I]   aliases gx region (P dead before k4 writes gx)
// ---------------------------------------------------------------------------
extern "C" void kernel_launch(void* const* d_in, const int* in_sizes, int n_in,
                              void* d_out, int out_size, void* d_ws, size_t ws_size,
                              hipStream_t stream) {
  const float* x   = (const float*)d_in[0];
  const float* Wih = (const float*)d_in[1];
  const float* Whh = (const float*)d_in[2];
  const float* bg  = (const float*)d_in[3];
  const float* W1  = (const float*)d_in[4];
  const float* b1  = (const float*)d_in[5];
  const float* W2  = (const float*)d_in[6];
  const float* b2  = (const float*)d_in[7];
  const float* Wfc = (const float*)d_in[8];
  const float* bfc = (const float*)d_in[9];
  float* out = (float*)d_out;

  float* wsf = (float*)d_ws;
  unsigned long long* Hx = (unsigned long long*)wsf;
  float* S    = wsf;
  float* E    = wsf + 655360;
  float* INVD = wsf + 1310720;
  float* Mm   = wsf + 1966080;
  float* hT   = wsf + 6160384;
  half2_t* Wq = (half2_t*)(wsf + 6176768);
  __half* gx  = (__half*)(wsf + 6307840);
  float* P    = wsf + 6307840;           // aliases gx region (disjoint in time)

  hipLaunchKernelGGL(k0_pack,   dim3(512),     dim3(256), 0, stream, Whh, Wq);
  hipLaunchKernelGGL(k1_scores, dim3(512),     dim3(256), 0, stream, x, W1, b1, W2, b2, S);
  hipLaunchKernelGGL(k2_prefix, dim3(B_ * R_), dim3(64),  0, stream, S, E, INVD);
  hipLaunchKernelGGL(k3a,       dim3(512),     dim3(128), 0, stream, x, E, P);
  hipLaunchKernelGGL(k3b,       dim3(640),     dim3(256), 0, stream, P);
  hipLaunchKernelGGL(k3c,       dim3(512),     dim3(128), 0, stream, x, E, INVD, P, Mm);
  hipLaunchKernelGGL(k4_gemm,   dim3(512, 16), dim3(256), 0, stream, Mm, Wih, bg, gx);
  hipLaunchKernelGGL(k_init,    dim3(64),      dim3(256), 0, stream, Hx);
  hipLaunchKernelGGL(k5_lstm,   dim3(256),     dim3(512), 0, stream, gx, Wq, Hx, hT);
  hipLaunchKernelGGL(k6_head,   dim3(B_),      dim3(64),  0, stream, hT, Wfc, bfc, out);
}